// Round 12
// baseline (21.243 us; speedup 1.0000x reference)
//
#include <hip/hip_runtime.h>

// ConvTranspose3d-via-FFT == circular 3^3 conv on 2x-upsampled grid.
// Parity decomposition (verified): out[b,i,2q+p] = sum_{j,t} We_p[i][j][t] * x[b,j,(q-t) mod 16]
//   p=0: t0 <- k0,    t1 <- k1+k2
//   p=1: t0 <- k0+k1, t1 <- k2     (per axis, circular mod 16)
//
// Round 12: FULL fusion, no grid sync, no workspace. One kernel, 256 blocks
// (1/CU) x 256 threads. Each block: (A) builds its (pd,ph) We-panel in LDS
// from raw weights (R9-verified contraction); (B) reads its own x-halo
// (4b x 64j x 2dd x 5hh x 16ww f32, L3-hot) straight from x, converts to
// bf16, ds_writes into R11's x_lds layout; (C) barrier; R11-verified MFMA
// compute + store. Removes prep launch, inter-kernel drain, xT round-trip.

typedef float f32x16 __attribute__((ext_vector_type(16)));
typedef short s16x8 __attribute__((ext_vector_type(8)));

#define CI  64
#define CO  32
#define QV  4096                     // 16^3
#define WE_BYTES 65536               // [plane16][c8][i32][e8] bf16
#define X_BYTES  81920               // [seg320 = bc*10+dhh][ww16][e8] bf16
#define LDS_BYTES (WE_BYTES + X_BYTES)   // 147456 <= 163840

__device__ __forceinline__ unsigned short f32_to_bf16_rne(float f) {
    union { float f; unsigned u; } v; v.f = f;
    unsigned u = v.u;
    unsigned r = u + 0x7FFFu + ((u >> 16) & 1u);
    return (unsigned short)(r >> 16);
}

__global__ __launch_bounds__(256)
void convt3d_fused_kernel(const float* __restrict__ x,
                          const float* __restrict__ weight,
                          float* __restrict__ out) {
    __shared__ __align__(16) char smem[LDS_BYTES];
    unsigned short* we_lds = (unsigned short*)smem;          // 64KB
    char* x_lds = smem + WE_BYTES;                           // 80KB

    const int blk = blockIdx.x;          // 256
    const int pp  = blk >> 6;            // (pd,ph)
    const int T2  = blk & 63;            // (qd, qh-quad)
    const int pd = pp >> 1, ph = pp & 1;
    const int qd = T2 >> 2, qhq = T2 & 3;

    const int w    = threadIdx.x >> 6;
    const int lane = threadIdx.x & 63;

    // ---- phase A: build (pd,ph) We panel in LDS from raw weights ----
    {
        const int c = threadIdx.x & 7;   // j-chunk
        const int i = threadIdx.x >> 3;  // output channel
        s16x8 pk[16];
        #pragma unroll
        for (int k = 0; k < 8; ++k) {    // e = k, j = c*8 + k
            const int j = c * 8 + k;
            const float* wp = weight + (i * CI + j) * 27;
            float wv[27];
            #pragma unroll
            for (int m = 0; m < 27; ++m) wv[m] = wp[m];

            float t1[2][9];
            #pragma unroll
            for (int m = 0; m < 9; ++m) {
                t1[0][m] = pd ? (wv[m] + wv[9 + m]) : wv[m];
                t1[1][m] = pd ? wv[18 + m] : (wv[9 + m] + wv[18 + m]);
            }
            #pragma unroll
            for (int td = 0; td < 2; ++td)
                #pragma unroll
                for (int th = 0; th < 2; ++th) {
                    float w0, w1, w2;
                    if (th == 0) {
                        w0 = ph ? (t1[td][0] + t1[td][3]) : t1[td][0];
                        w1 = ph ? (t1[td][1] + t1[td][4]) : t1[td][1];
                        w2 = ph ? (t1[td][2] + t1[td][5]) : t1[td][2];
                    } else {
                        w0 = ph ? t1[td][6] : (t1[td][3] + t1[td][6]);
                        w1 = ph ? t1[td][7] : (t1[td][4] + t1[td][7]);
                        w2 = ph ? t1[td][8] : (t1[td][5] + t1[td][8]);
                    }
                    const int tb = td * 4 + th * 2;
                    pk[tb + 0][k]     = (short)f32_to_bf16_rne(w0);        // pw0,tw0
                    pk[tb + 1][k]     = (short)f32_to_bf16_rne(w1 + w2);   // pw0,tw1
                    pk[8 + tb + 0][k] = (short)f32_to_bf16_rne(w0 + w1);   // pw1,tw0
                    pk[8 + tb + 1][k] = (short)f32_to_bf16_rne(w2);        // pw1,tw1
                }
        }
        #pragma unroll
        for (int plane = 0; plane < 16; ++plane)
            *reinterpret_cast<s16x8*>(we_lds + ((plane * 8 + c) * 32 + i) * 8) = pk[plane];
    }

    // ---- phase B: x halo -> x_lds bf16. 320 segs; lane = (g=lane>>4, ww) ----
    {
        #pragma unroll
        for (int k = 0; k < 20; ++k) {
            const int seg = (w * 20 + k) * 4 + (lane >> 4);   // 0..319
            const int ww  = lane & 15;
            const int bc  = seg / 10;                          // b*8 + c
            const int dhh = seg - bc * 10;
            const int dd_i = (dhh >= 5) ? 1 : 0;
            const int hh_i = dhh - dd_i * 5;
            const int dd = (qd - 1 + dd_i) & 15;
            const int hh = (qhq * 4 - 1 + hh_i) & 15;
            // x[b][c*8+e][dd][hh][ww]; (b*64 + c*8) == bc*8
            const float* src = x + (size_t)bc * 8 * QV + dd * 256 + hh * 16 + ww;
            s16x8 pk;
            #pragma unroll
            for (int e = 0; e < 8; ++e)
                pk[e] = (short)f32_to_bf16_rne(src[e * QV]);
            *reinterpret_cast<s16x8*>(x_lds + seg * 256 + ww * 16) = pk;
        }
    }

    __syncthreads();

    // ---- phase C: MFMA compute (verified R11) ----
    const int b    = w;                  // wave = batch
    const int n    = lane & 31;
    const int half = lane >> 5;
    const int qw   = n & 15;
    const int hsel = n >> 4;

    f32x16 acc00 = {}, acc01 = {};   // tau=0, pw=0/1
    f32x16 acc10 = {}, acc11 = {};   // tau=1, pw=0/1

    #pragma unroll
    for (int t = 0; t < 8; ++t) {
        const int td = t >> 2, th = (t >> 1) & 1, tw = t & 1;
        const int dd_i = 1 - td;
        const int ww = (qw - tw) & 15;
        const int hbase = dd_i * 5 + hsel + 1 - th;   // hh_i for tau=0
        #pragma unroll
        for (int ks = 0; ks < 4; ++ks) {
            const int c  = 2 * ks + half;
            const int bc = b * 8 + c;
            const s16x8 b0 = *reinterpret_cast<const s16x8*>(
                x_lds + (bc * 10 + hbase) * 256 + ww * 16);
            const s16x8 b1 = *reinterpret_cast<const s16x8*>(
                x_lds + (bc * 10 + hbase + 2) * 256 + ww * 16);
            const s16x8 a0 = *reinterpret_cast<const s16x8*>(
                we_lds + ((t * 8 + c) * 32 + n) * 8);
            const s16x8 a1 = *reinterpret_cast<const s16x8*>(
                we_lds + (((8 + t) * 8 + c) * 32 + n) * 8);
            acc00 = __builtin_amdgcn_mfma_f32_32x32x16_bf16(a0, b0, acc00, 0, 0, 0);
            acc01 = __builtin_amdgcn_mfma_f32_32x32x16_bf16(a1, b0, acc01, 0, 0, 0);
            acc10 = __builtin_amdgcn_mfma_f32_32x32x16_bf16(a0, b1, acc10, 0, 0, 0);
            acc11 = __builtin_amdgcn_mfma_f32_32x32x16_bf16(a1, b1, acc11, 0, 0, 0);
        }
    }

    // ---- store: D layout col n, row m=(r&3)+8*(r>>2)+4*half ----
    const int d = 2 * qd + pd;
    #pragma unroll
    for (int tau = 0; tau < 2; ++tau) {
        const int h = 2 * (4 * qhq + 2 * tau + hsel) + ph;
        float* ob = out + ((size_t)b * CO) * 32768 + d * 1024 + h * 32 + 2 * qw;
        #pragma unroll
        for (int r = 0; r < 16; ++r) {
            const int m = (r & 3) + 8 * (r >> 2) + 4 * half;
            float2 v;
            if (tau == 0) { v.x = acc00[r]; v.y = acc01[r]; }
            else          { v.x = acc10[r]; v.y = acc11[r]; }
            *reinterpret_cast<float2*>(ob + (size_t)m * 32768) = v;
        }
    }
}

extern "C" void kernel_launch(void* const* d_in, const int* in_sizes, int n_in,
                              void* d_out, int out_size, void* d_ws, size_t ws_size,
                              hipStream_t stream) {
    const float* x      = (const float*)d_in[0];
    const float* weight = (const float*)d_in[1];
    float* out          = (float*)d_out;

    convt3d_fused_kernel<<<256, 256, 0, stream>>>(x, weight, out);
}